// Round 4
// baseline (170.075 us; speedup 1.0000x reference)
//
#include <hip/hip_runtime.h>
#include <hip/hip_cooperative_groups.h>

// Simple1DSSM fused single cooperative kernel.
// y = causal conv of x (64 x 8192) with SSM kernel K[m] = C diag(r^m) Bb, done as a
// chunk-parallel diagonal-state scan with a grid.sync() between phases:
//   tables (per-block LDS): MtX[d][i] = C_d r_d^i (stride 65), Bb[d], Kp[63+m] = K[m]
//   phase 1: hloc[b][c][d] = Bb_d * sum_j r_d^{63-j} x[b,c*64+j] -> ws
//   grid.sync()
//   phase 2: g_d = sum_{c'<c} (r_d^64)^{c-1-c'} hloc[b][c'][d]  (self-truncating)
//            y[b,c*64+i] = sum_d MtX[d][i+1] g_d + sum_{j<=i} K[i-j] x[b,c*64+j]

#define SEQ_L 8192
#define TCH   64
#define NCH   128
#define NB    64
#define NBLK  1024   // 4 blocks/CU, 4 waves each -> exactly co-resident

namespace cg = cooperative_groups;

__device__ __forceinline__ float rl(float v, int l) {
    return __int_as_float(__builtin_amdgcn_readlane(__float_as_int(v), l));
}

__global__ __launch_bounds__(256, 4) void ssm_fused(const float* __restrict__ x,
                                                    const float* __restrict__ A,
                                                    const float* __restrict__ B,
                                                    const float* __restrict__ C,
                                                    const float* __restrict__ logd,
                                                    float* __restrict__ ws,
                                                    float* __restrict__ out)
{
    __shared__ float MtX[65 * 64];   // MtX[d*65 + i] = C_d * r_d^i, i in [0,64]
    __shared__ float Kp[127];        // Kp[63+m] = K[m], Kp[m<63] = 0
    __shared__ float BbS[64];

    const float delta = expf(logd[0]);
    const int tid  = threadIdx.x;
    const int lane = tid & 63;
    const int wv   = tid >> 6;

    // ---- per-block table build (parallel) ----
    for (int e = tid; e < 65 * 64; e += 256) {
        const int d = e / 65;
        const int i = e - d * 65;
        MtX[e] = C[d] * expf((float)i * delta * A[d]);
    }
    if (tid < 63) Kp[tid] = 0.f;
    if (wv == 1) {
        const float rd = expf(delta * A[lane]);
        BbS[lane] = (rd - 1.f) / A[lane] * B[lane];
    }
    __syncthreads();
    if (wv == 0) {
        // lane m: K[m] = sum_d Bb_d * C_d r_d^m   (MtX read: bank (d+m)%32, conflict-free)
        float s = 0.f;
        #pragma unroll 8
        for (int d = 0; d < 64; ++d)
            s = fmaf(BbS[d], MtX[d * 65 + lane], s);
        Kp[63 + lane] = s;
    }

    // ---- phase 1: chunk-local end states (2 units per wave) ----
    const float dAd = delta * A[lane];
    const float r   = expf(dAd);
    const float r32 = expf(32.f * dAd);
    const float rT  = r32 * r32;                 // r^64
    const float Bbl = (r - 1.f) / A[lane] * B[lane];

    const int u0   = blockIdx.x * 8 + wv * 2;    // units u0, u0+1 (same batch: c even)
    const int b0   = u0 >> 7;
    const int c0   = u0 & (NCH - 1);
    const int base0 = b0 * SEQ_L + c0 * TCH;

    const float xa = x[base0 + lane];
    const float xb = x[base0 + TCH + lane];
    float h0a = 0.f, h1a = 0.f, h0b = 0.f, h1b = 0.f;
    #pragma unroll
    for (int j = 0; j < 32; ++j) {
        h0a = fmaf(r, h0a, rl(xa, j));
        h0b = fmaf(r, h0b, rl(xb, j));
    }
    #pragma unroll
    for (int j = 32; j < 64; ++j) {
        h1a = fmaf(r, h1a, rl(xa, j));
        h1b = fmaf(r, h1b, rl(xb, j));
    }
    ws[u0 * 64 + lane]       = Bbl * fmaf(r32, h0a, h1a);
    ws[(u0 + 1) * 64 + lane] = Bbl * fmaf(r32, h0b, h1b);

    __threadfence();
    cg::this_grid().sync();

    // ---- phase 2: incoming state + outputs (same 2 units) ----
    #pragma unroll
    for (int k = 0; k < 2; ++k) {
        const int u    = u0 + k;
        const int b    = u >> 7;
        const int c    = u & (NCH - 1);
        const int base = b * SEQ_L + c * TCH;

        // self-truncating cross-chunk state sum (lane = d)
        float g = 0.f, w = 1.f;
        const float* hl = ws + (b * NCH) * 64;
        for (int cp = c - 1; cp >= 0; --cp) {
            g = fmaf(w, hl[cp * 64 + lane], g);
            w *= rT;
            if (!__any(w > 1e-14f)) break;
        }

        const float xs = x[base + lane];
        float acc0 = 0.f, acc1 = 0.f;
        #pragma unroll
        for (int d = 0; d < 64; d += 2) {
            acc0 = fmaf(MtX[d * 65 + lane + 1],       rl(g, d),     acc0);
            acc1 = fmaf(MtX[(d + 1) * 65 + lane + 1], rl(g, d + 1), acc1);
        }
        #pragma unroll
        for (int j = 0; j < 64; j += 2) {
            acc0 = fmaf(Kp[63 + lane - j], rl(xs, j),     acc0);
            acc1 = fmaf(Kp[62 + lane - j], rl(xs, j + 1), acc1);
        }
        out[base + lane] = acc0 + acc1;
    }
}

extern "C" void kernel_launch(void* const* d_in, const int* in_sizes, int n_in,
                              void* d_out, int out_size, void* d_ws, size_t ws_size,
                              hipStream_t stream) {
    const float* x    = (const float*)d_in[0];
    const float* A    = (const float*)d_in[1];
    const float* B    = (const float*)d_in[2];
    const float* C    = (const float*)d_in[3];
    const float* logd = (const float*)d_in[4];
    float* out = (float*)d_out;
    float* ws  = (float*)d_ws;   // uses 8192*64 floats (2 MB)

    void* args[] = { (void*)&x, (void*)&A, (void*)&B, (void*)&C,
                     (void*)&logd, (void*)&ws, (void*)&out };
    hipLaunchCooperativeKernel((void*)ssm_fused, dim3(NBLK), dim3(256),
                               args, 0, stream);
}

// Round 5
// 24.591 us; speedup vs baseline: 6.9162x; 6.9162x over previous
//
#include <hip/hip_runtime.h>

// Simple1DSSM as a runtime-truncated causal FIR (exact decay bound, adaptive depth).
// K[m] = sum_d w_d r_d^m, w_d = C_d*Bb_d, r_d = exp(delta*A_d) <= e^-delta (A_d <= -1).
// Tail bound: sum_{m>=M}|K[m]| <= e^{-delta*M} * sum_d |w_d|/(1-r_d)  -> per-block
// uniform tap-count decision. Always-built taps m in [0,257); extended region up to
// m<1920 built only if the bound requires (delta tiny). One plain kernel, no sync.

#define SEQ_L 8192
#define TCH   64
#define NCH   128
#define NB    64
#define KLEN  1983     // KALL[k] = K[k-63]; zeros for k<63 (m<0)
#define PMAX  30       // max 64-tap blocks -> m < 1920

__device__ __forceinline__ float rl(float v, int l) {
    return __int_as_float(__builtin_amdgcn_readlane(__float_as_int(v), l));
}

__global__ __launch_bounds__(256) void ssm_fir(const float* __restrict__ x,
                                               const float* __restrict__ A,
                                               const float* __restrict__ B,
                                               const float* __restrict__ C,
                                               const float* __restrict__ logd,
                                               float* __restrict__ out)
{
    __shared__ float KALL[KLEN];
    __shared__ float sW[64], sDA[64], sT[64];

    const int tid  = threadIdx.x;
    const int lane = tid & 63;
    const float delta = __expf(logd[0]);

    if (tid < 64) {
        const float Ad = A[tid];
        const float dA = delta * Ad;
        const float r  = __expf(dA);
        const float Bb = (r - 1.f) / Ad * B[tid];
        const float w  = C[tid] * Bb;
        sW[tid]  = w;
        sDA[tid] = dA;
        sT[tid]  = fabsf(w) / (1.f - r);
    }
    __syncthreads();

    // ---- K table build (always-region k in [0,320)) + tail-bound scale sden ----
    float sden = 0.f;
    {
        const int  m1  = tid - 63;          // k = tid
        const int  m2  = tid + 193;         // k = 256+tid (tid<64 only)
        const bool two = (tid < 64);        // wave-uniform
        float k1 = 0.f, k2 = 0.f;
        for (int d = 0; d < 64; ++d) {
            const float wd = sW[d], da = sDA[d];
            sden += sT[d];
            if (m1 >= 0) k1 = fmaf(wd, __expf((float)m1 * da), k1);
            if (two)     k2 = fmaf(wd, __expf((float)m2 * da), k2);
        }
        KALL[tid] = (m1 >= 0) ? k1 : 0.f;
        if (two) KALL[256 + tid] = k2;
    }
    // extended region (rare: tiny delta). Condition matches the p>=4 loop test with margin.
    if (6.f * sden * __expf(-193.f * delta) > 0.5e-4f) {
        for (int k = 320 + tid; k < KLEN; k += 256) {
            const float m = (float)(k - 63);
            float s = 0.f;
            for (int d = 0; d < 64; ++d)
                s = fmaf(sW[d], __expf(m * sDA[d]), s);
            KALL[k] = s;
        }
    }
    __syncthreads();

    // ---- direct conv: one wave per (b,c) chunk of 64 outputs ----
    const int unit  = blockIdx.x * 4 + (tid >> 6);
    const int b     = unit >> 7;
    const int c     = unit & (NCH - 1);
    const int xbase = b * SEQ_L + c * TCH;

    const float wq = __expf(-64.f * delta);
    float wtail = 6.f * sden * __expf(-delta);   // bound on blocks >= 1
    float acc0 = 0.f, acc1 = 0.f;
    int p = 0;
    while (true) {
        const float xp = x[xbase - p * TCH + lane];
        const int   kb = lane + 64 * p;          // KALL index = kb + (63 - j)
        #pragma unroll
        for (int j = 0; j < 64; j += 2) {
            acc0 = fmaf(KALL[kb + 63 - j], rl(xp, j),     acc0);
            acc1 = fmaf(KALL[kb + 62 - j], rl(xp, j + 1), acc1);
        }
        ++p;
        if (p > c || p >= PMAX || wtail <= 1e-4f) break;
        wtail *= wq;
    }
    out[xbase + lane] = acc0 + acc1;
}

extern "C" void kernel_launch(void* const* d_in, const int* in_sizes, int n_in,
                              void* d_out, int out_size, void* d_ws, size_t ws_size,
                              hipStream_t stream) {
    const float* x    = (const float*)d_in[0];
    const float* A    = (const float*)d_in[1];
    const float* B    = (const float*)d_in[2];
    const float* C    = (const float*)d_in[3];
    const float* logd = (const float*)d_in[4];
    float* out = (float*)d_out;

    ssm_fir<<<(NB * NCH) / 4, 256, 0, stream>>>(x, A, B, C, logd, out);
}

// Round 6
// 10.434 us; speedup vs baseline: 16.2995x; 2.3567x over previous
//
#include <hip/hip_runtime.h>

// Simple1DSSM as an adaptively-truncated causal FIR.
// K[m] = sum_d w_d r_d^m, w_d = C_d*Bb_d, r_d = exp(delta*A_d) <= e^-delta (A_d <= -1).
// Grid-uniform tap count M from the exact tail bound:
//   sum_{m>=M}|K[m]| <= sden * e^{-delta*M},  sden = sum_d |w_d|/(1-r_d)
//   M = ceil((ln(sden)+11.6)/delta)  ->  tail*maxX ~ 4e-5  (clamped to [1,1536]).
// One thread per output; block = 256 consecutive outputs of one batch row.
// x window + halo staged in LDS (zero-filled across the batch boundary).

#define SEQ_L 8192
#define NB    64
#define MCAP  1536
#define XWIN  (MCAP + 256)

__global__ __launch_bounds__(256) void ssm_fir(const float* __restrict__ x,
                                               const float* __restrict__ A,
                                               const float* __restrict__ B,
                                               const float* __restrict__ C,
                                               const float* __restrict__ logd,
                                               float* __restrict__ out)
{
    __shared__ float Kl[MCAP];
    __shared__ float xL[XWIN];
    __shared__ float sW[64], sDA[64];
    __shared__ int   sM;

    const int tid = threadIdx.x;
    const float delta = __expf(logd[0]);

    // ---- per-d params + grid-uniform tap count M (wave 0) ----
    if (tid < 64) {
        const float Ad = A[tid];
        const float dA = delta * Ad;
        const float r  = __expf(dA);
        const float w  = C[tid] * (r - 1.f) / Ad * B[tid];
        sW[tid]  = w;
        sDA[tid] = dA;
        float t = fabsf(w) / (1.f - r);
        #pragma unroll
        for (int off = 32; off; off >>= 1) t += __shfl_xor(t, off);
        if (tid == 0) {
            const int M = (int)ceilf((logf(t) + 11.6f) / delta);
            sM = min(max(M, 1), MCAP);
        }
    }
    __syncthreads();
    const int M = sM;
    const int H = (M + 63) & ~63;     // halo, multiple of 64, >= M

    // ---- build K[0..M): 4 threads per tap, 16 d's each, shfl-combine ----
    for (int mb = tid >> 2; mb < M; mb += 64) {
        const int d0 = (tid & 3) * 16;
        const float fm = (float)mb;
        float s = 0.f;
        #pragma unroll
        for (int dd = 0; dd < 16; ++dd) {
            const int d = d0 + dd;
            s = fmaf(sW[d], __expf(fm * sDA[d]), s);
        }
        s += __shfl_xor(s, 1);
        s += __shfl_xor(s, 2);
        if ((tid & 3) == 0) Kl[mb] = s;
    }

    // ---- stage x window [t0-H, t0+256) of this batch row ----
    const int b  = blockIdx.x >> 5;          // 32 blocks per batch row
    const int t0 = (blockIdx.x & 31) * 256;  // within-row start
    const float* xb = x + b * SEQ_L;
    for (int s = tid; s < H + 256; s += 256) {
        const int t = t0 - H + s;
        xL[s] = (t >= 0) ? xb[t] : 0.f;      // zero-fill before row start
    }
    __syncthreads();

    // ---- conv: output t0 + tid;  K broadcast-read, x lane-consecutive ----
    const int base = H + tid;
    float a0 = 0.f, a1 = 0.f;
    int m = 0;
    for (; m + 2 <= M; m += 2) {
        a0 = fmaf(Kl[m],     xL[base - m],     a0);
        a1 = fmaf(Kl[m + 1], xL[base - m - 1], a1);
    }
    if (m < M) a0 = fmaf(Kl[m], xL[base - m], a0);
    out[b * SEQ_L + t0 + tid] = a0 + a1;
}

extern "C" void kernel_launch(void* const* d_in, const int* in_sizes, int n_in,
                              void* d_out, int out_size, void* d_ws, size_t ws_size,
                              hipStream_t stream) {
    const float* x    = (const float*)d_in[0];
    const float* A    = (const float*)d_in[1];
    const float* B    = (const float*)d_in[2];
    const float* C    = (const float*)d_in[3];
    const float* logd = (const float*)d_in[4];
    float* out = (float*)d_out;

    ssm_fir<<<(NB * SEQ_L) / 256, 256, 0, stream>>>(x, A, B, C, logd, out);
}

// Round 7
// 10.006 us; speedup vs baseline: 16.9968x; 1.0428x over previous
//
#include <hip/hip_runtime.h>

// Simple1DSSM as an adaptively-truncated causal FIR, 4 outputs/thread, float4 everywhere.
// K[m] = sum_d w_d r_d^m, w_d = C_d*Bb_d, r_d = exp(delta*A_d) <= e^-delta (A_d <= -1).
// Grid-uniform tap count M from the exact tail bound:
//   sum_{m>=M}|K[m]| <= sden * e^{-delta*M},  M = ceil((ln(sden)+11.6)/delta), clamped.
// Block = 1024 consecutive outputs of one batch row; x window + halo in LDS
// (zero-filled across the batch boundary). Conv: per 4 taps load float4 K (uniform)
// + float4 x, 8-value sliding register window, 16 FMAs.

#define SEQ_L 8192
#define NB    64
#define MCAP  1532               // M clamp; M4 = (M+3)&~3 <= 1532, H <= 1536
#define XWIN  (1536 + 1024)

__global__ __launch_bounds__(256) void ssm_fir(const float* __restrict__ x,
                                               const float* __restrict__ A,
                                               const float* __restrict__ B,
                                               const float* __restrict__ C,
                                               const float* __restrict__ logd,
                                               float* __restrict__ out)
{
    __shared__ __align__(16) float Kl[1536];
    __shared__ __align__(16) float xL[XWIN];
    __shared__ float sW[64], sDA[64];
    __shared__ int   sM;

    const int tid = threadIdx.x;
    const float delta = __expf(logd[0]);

    // ---- per-d params + grid-uniform tap count M (wave 0) ----
    if (tid < 64) {
        const float Ad = A[tid];
        const float dA = delta * Ad;
        const float r  = __expf(dA);
        const float w  = C[tid] * (r - 1.f) / Ad * B[tid];
        sW[tid]  = w;
        sDA[tid] = dA;
        float t = fabsf(w) / (1.f - r);
        #pragma unroll
        for (int off = 32; off; off >>= 1) t += __shfl_xor(t, off);
        if (tid == 0) {
            const int M = (int)ceilf((logf(t) + 11.6f) / delta);
            sM = min(max(M, 1), MCAP);
        }
    }
    __syncthreads();
    const int M4 = (sM + 3) & ~3;       // taps, multiple of 4
    const int H  = (M4 & ~63) + 64;     // halo: multiple of 64, >= M4 + 4

    // ---- build K[0..M4): 4 threads per tap, 16 d's each, shfl-combine ----
    for (int mb = tid >> 2; mb < M4; mb += 64) {
        const int d0 = (tid & 3) * 16;
        const float fm = (float)mb;
        float s = 0.f;
        #pragma unroll
        for (int dd = 0; dd < 16; ++dd) {
            const int d = d0 + dd;
            s = fmaf(sW[d], __expf(fm * sDA[d]), s);
        }
        s += __shfl_xor(s, 1);
        s += __shfl_xor(s, 2);
        if ((tid & 3) == 0) Kl[mb] = s;
    }

    // ---- stage x window [t0-H, t0+1024) of this batch row (float4) ----
    const int b  = blockIdx.x >> 3;          // 8 blocks per batch row
    const int t0 = (blockIdx.x & 7) * 1024;  // within-row start
    const float* xb = x + b * SEQ_L;
    const int n4 = (H + 1024) >> 2;
    for (int s4 = tid; s4 < n4; s4 += 256) {
        const int t = t0 - H + s4 * 4;       // multiple of 4, 16B-aligned
        float4 v = make_float4(0.f, 0.f, 0.f, 0.f);
        if (t >= 0) v = *(const float4*)(xb + t);
        *(float4*)(xL + s4 * 4) = v;
    }
    __syncthreads();

    // ---- conv: outputs t0 + tid*4 .. +3 ----
    const int base = H + tid * 4;            // xL coord of output j=0
    float4 Wlo = *(const float4*)(xL + base - 4);   // W[0..3] = xL[base-4 .. base-1]
    float4 Whi = *(const float4*)(xL + base);       // W[4..7] = xL[base .. base+3]
    float a0 = 0.f, a1 = 0.f, a2 = 0.f, a3 = 0.f;
    for (int m0 = 0; m0 < M4; m0 += 4) {
        const float4 Kv = *(const float4*)(Kl + m0);   // wave-uniform broadcast
        // tap m0+t uses x[base + j - m0 - t] = W[4 + j - t]
        a0 = fmaf(Kv.x, Whi.x, a0); a1 = fmaf(Kv.x, Whi.y, a1);
        a2 = fmaf(Kv.x, Whi.z, a2); a3 = fmaf(Kv.x, Whi.w, a3);
        a0 = fmaf(Kv.y, Wlo.w, a0); a1 = fmaf(Kv.y, Whi.x, a1);
        a2 = fmaf(Kv.y, Whi.y, a2); a3 = fmaf(Kv.y, Whi.z, a3);
        a0 = fmaf(Kv.z, Wlo.z, a0); a1 = fmaf(Kv.z, Wlo.w, a1);
        a2 = fmaf(Kv.z, Whi.x, a2); a3 = fmaf(Kv.z, Whi.y, a3);
        a0 = fmaf(Kv.w, Wlo.y, a0); a1 = fmaf(Kv.w, Wlo.z, a1);
        a2 = fmaf(Kv.w, Wlo.w, a2); a3 = fmaf(Kv.w, Whi.x, a3);
        Whi = Wlo;
        Wlo = *(const float4*)(xL + base - m0 - 8);  // >= xL[0] since H >= M4+4
    }
    *(float4*)(out + b * SEQ_L + t0 + tid * 4) = make_float4(a0, a1, a2, a3);
}

extern "C" void kernel_launch(void* const* d_in, const int* in_sizes, int n_in,
                              void* d_out, int out_size, void* d_ws, size_t ws_size,
                              hipStream_t stream) {
    const float* x    = (const float*)d_in[0];
    const float* A    = (const float*)d_in[1];
    const float* B    = (const float*)d_in[2];
    const float* C    = (const float*)d_in[3];
    const float* logd = (const float*)d_in[4];
    float* out = (float*)d_out;

    ssm_fir<<<NB * 8, 256, 0, stream>>>(x, A, B, C, logd, out);
}